// Round 1
// baseline (224.433 us; speedup 1.0000x reference)
//
#include <hip/hip_runtime.h>
#include <hip/hip_bf16.h>

// DLRM-like: B=16384, dense 13 -> MLP [512,256,64], 26 embeddings of dim 64,
// pairwise-dot interaction (325 pairs), top GEMM (64+325=389 -> 256).
//
// ws layout:
//   [0, 33.5MB):  X1 (16384x512 f32), later reused as features (16384x400 f32)
//   [33.5MB, 50.3MB): X2 (16384x256 f32)

#define BATCH     16384
#define NDENSE    13
#define NSPARSE   26
#define VOCAB     100000
#define EMB       64
#define FSTRIDE   400   // 64 dense_out + 325 interact + 11 zero pad
#define TOPK_REAL 389

// ---------------------------------------------------------------- mlp0 ----
// X1 = relu(D @ W0 + b0), D: B x 13, W0: 13 x 512. W0+b0 staged in LDS.
// block = 512 threads (1 thread per output col), 8 rows per block.
__global__ __launch_bounds__(512)
void mlp0_kernel(const float* __restrict__ D, const float* __restrict__ W0,
                 const float* __restrict__ b0, float* __restrict__ X1)
{
    __shared__ float w[NDENSE * 512];
    __shared__ float bb[512];
    __shared__ float drow[8][NDENSE];

    int tid = threadIdx.x;
    for (int i = tid; i < NDENSE * 512; i += 512) w[i] = W0[i];
    bb[tid] = b0[tid];
    int rbase = blockIdx.x * 8;
    if (tid < 8 * NDENSE)
        drow[tid / NDENSE][tid % NDENSE] = D[(size_t)(rbase + tid / NDENSE) * NDENSE + tid % NDENSE];
    __syncthreads();

    int j = tid;
    for (int r = 0; r < 8; ++r) {
        float acc = bb[j];
        #pragma unroll
        for (int k = 0; k < NDENSE; ++k) acc += drow[r][k] * w[k * 512 + j];
        X1[(size_t)(rbase + r) * 512 + j] = fmaxf(acc, 0.f);
    }
}

// ------------------------------------------------- generic tiled SGEMM ----
// C[M x N] = act(A[M x Kpad(lda)] @ W[Kreal x N] + bias), 64x64 tile,
// 4x4 microtile per thread, BK=16. Rows of W with k >= Kreal staged as zero
// (A's padded cols are zero, but we must not read W out of bounds).
#define BM 64
#define BN 64
#define BK 16

__global__ __launch_bounds__(256)
void gemm_bias_act(const float* __restrict__ A, int lda,
                   const float* __restrict__ W,
                   const float* __restrict__ bias,
                   float* __restrict__ C, int ldc,
                   int Kpad, int Kreal, int N, int do_relu)
{
    __shared__ float As[BK][BM];   // transposed: As[k][m]
    __shared__ float Bs[BK][BN];

    int tid = threadIdx.x;
    int tr = tid >> 4;         // 0..15 -> row group
    int tc = tid & 15;         // 0..15 -> col group
    int m0 = blockIdx.x * BM;
    int n0 = blockIdx.y * BN;

    // A staging: thread loads float4 along k. 64 rows x 16 k.
    int ar = tid >> 2;           // 0..63
    int ak = (tid & 3) * 4;      // 0,4,8,12
    // B staging: 16 rows x 64 cols, float4 along n.
    int br = tid >> 4;           // 0..15
    int bj = (tid & 15) * 4;     // 0..60

    float acc[4][4] = {};

    for (int k0 = 0; k0 < Kpad; k0 += BK) {
        float4 av = *(const float4*)(A + (size_t)(m0 + ar) * lda + k0 + ak);
        As[ak + 0][ar] = av.x;
        As[ak + 1][ar] = av.y;
        As[ak + 2][ar] = av.z;
        As[ak + 3][ar] = av.w;

        int kg = k0 + br;
        float4 bv = make_float4(0.f, 0.f, 0.f, 0.f);
        if (kg < Kreal) bv = *(const float4*)(W + (size_t)kg * N + n0 + bj);
        *(float4*)&Bs[br][bj] = bv;
        __syncthreads();

        #pragma unroll
        for (int kk = 0; kk < BK; ++kk) {
            float4 a = *(const float4*)&As[kk][tr * 4];
            float4 b = *(const float4*)&Bs[kk][tc * 4];
            float ai[4] = {a.x, a.y, a.z, a.w};
            float bj4[4] = {b.x, b.y, b.z, b.w};
            #pragma unroll
            for (int i = 0; i < 4; ++i)
                #pragma unroll
                for (int jn = 0; jn < 4; ++jn)
                    acc[i][jn] += ai[i] * bj4[jn];
        }
        __syncthreads();
    }

    #pragma unroll
    for (int i = 0; i < 4; ++i) {
        int r = m0 + tr * 4 + i;
        #pragma unroll
        for (int jn = 0; jn < 4; ++jn) {
            int j = n0 + tc * 4 + jn;
            float v = acc[i][jn] + bias[j];
            if (do_relu) v = fmaxf(v, 0.f);
            C[(size_t)r * ldc + j] = v;
        }
    }
}

// ------------------------------------------------------------ interact ----
// One block (256 thr) per sample: gather 26 embedding rows into LDS, then
// 325 pairwise dots -> features[s][64 + p]. Also zeros pad cols 389..399.
#define ESTR 66   // stride 66: (j*66+d)%32 = (2j+d)%32 -> conflict-friendly

__global__ __launch_bounds__(256)
void interact_kernel(const int* __restrict__ sparse,
                     const float* __restrict__ tables,
                     float* __restrict__ feat)
{
    __shared__ float e[NSPARSE * ESTR];

    int s = blockIdx.x;
    int tid = threadIdx.x;
    int wv = tid >> 6;
    int lane = tid & 63;

    for (int i = wv; i < NSPARSE; i += 4) {
        int idx = sparse[s * NSPARSE + i];   // wave-uniform
        e[i * ESTR + lane] = tables[((long)i * VOCAB + idx) * EMB + lane];
    }
    __syncthreads();

    for (int p = tid; p < 325; p += 256) {
        int pi = p, i = 0;
        while (pi >= (NSPARSE - 1) - i) { pi -= (NSPARSE - 1) - i; ++i; }
        int j = i + 1 + pi;
        const float* ei = &e[i * ESTR];
        const float* ej = &e[j * ESTR];
        float acc = 0.f;
        #pragma unroll
        for (int d = 0; d < EMB; d += 2) {
            float2 a = *(const float2*)(ei + d);
            float2 b = *(const float2*)(ej + d);
            acc += a.x * b.x + a.y * b.y;
        }
        feat[(size_t)s * FSTRIDE + 64 + p] = acc;
    }
    if (tid < FSTRIDE - TOPK_REAL)
        feat[(size_t)s * FSTRIDE + TOPK_REAL + tid] = 0.f;
}

// -------------------------------------------------------------- launch ----
extern "C" void kernel_launch(void* const* d_in, const int* in_sizes, int n_in,
                              void* d_out, int out_size, void* d_ws, size_t ws_size,
                              hipStream_t stream)
{
    const float* dense  = (const float*)d_in[0];
    const int*   sparse = (const int*)  d_in[1];
    const float* tables = (const float*)d_in[2];
    const float* W0     = (const float*)d_in[3];
    const float* b0     = (const float*)d_in[4];
    const float* W1     = (const float*)d_in[5];
    const float* b1     = (const float*)d_in[6];
    const float* W2     = (const float*)d_in[7];
    const float* b2     = (const float*)d_in[8];
    const float* Wt     = (const float*)d_in[9];
    const float* bt     = (const float*)d_in[10];
    float* out = (float*)d_out;

    float* X1   = (float*)d_ws;                                   // 16384x512
    float* feat = (float*)d_ws;                                   // reuses X1
    float* X2   = (float*)((char*)d_ws + (size_t)BATCH * 512 * 4);// 16384x256

    // 1) X1 = relu(D @ W0 + b0)
    mlp0_kernel<<<BATCH / 8, 512, 0, stream>>>(dense, W0, b0, X1);

    // 2) X2 = relu(X1 @ W1 + b1)   (M=16384, N=256, K=512)
    {
        dim3 g(BATCH / BM, 256 / BN);
        gemm_bias_act<<<g, 256, 0, stream>>>(X1, 512, W1, b1, X2, 256,
                                             512, 512, 256, 1);
    }

    // 3) feat[:, 0:64] = relu(X2 @ W2 + b2)   (M=16384, N=64, K=256)
    {
        dim3 g(BATCH / BM, 64 / BN);
        gemm_bias_act<<<g, 256, 0, stream>>>(X2, 256, W2, b2, feat, FSTRIDE,
                                             256, 256, 64, 1);
    }

    // 4) feat[:, 64:389] = pairwise dots; feat[:, 389:400] = 0
    interact_kernel<<<BATCH, 256, 0, stream>>>(sparse, tables, feat);

    // 5) out = feat @ Wt + bt   (M=16384, N=256, K=389 padded to 400)
    {
        dim3 g(BATCH / BM, 256 / BN);
        gemm_bias_act<<<g, 256, 0, stream>>>(feat, FSTRIDE, Wt, bt, out, 256,
                                             FSTRIDE, TOPK_REAL, 256, 0);
    }
}

// Round 2
// 128.379 us; speedup vs baseline: 1.7482x; 1.7482x over previous
//
#include <hip/hip_runtime.h>
#include <hip/hip_bf16.h>

// DLRM-like, bf16-MFMA version.
// B=16384; dense 13 -> [512,256,64]; 26 x emb64 gather; 325 pair dots;
// top GEMM (389 -> 256, K padded to 416).
//
// ws layout (bytes):
//   [0,          16777216)  X1b   16384x512 bf16
//   [16777216,   25165824)  X2b   16384x256 bf16
//   [25165824,   38797312)  featb 16384x416 bf16
//   [38797312,   39059456)  W1t   256x512  bf16
//   [39059456,   39092224)  W2t   64x256   bf16
//   [39092224,   39305216)  Wtt   256x416  bf16 (k>=389 zero)

#define BATCH     16384
#define NDENSE    13
#define NSPARSE   26
#define VOCAB     100000
#define EMB       64
#define FSTR      416    // 64 dense + 325 interact + 27 zero pad (mult of 32)
#define KREAL     389

typedef __attribute__((ext_vector_type(8))) short bf16x8;
typedef __attribute__((ext_vector_type(4))) float f32x4;

__device__ inline void gload_lds16(const void* g, void* l) {
    __builtin_amdgcn_global_load_lds(
        (const __attribute__((address_space(1))) void*)g,
        (__attribute__((address_space(3))) void*)l, 16, 0, 0);
}

// ----------------------------------------------------------------- prep ----
// Convert + transpose weights to bf16 NT form.
__global__ __launch_bounds__(256)
void prep_weights(const float* __restrict__ W1, const float* __restrict__ W2,
                  const float* __restrict__ Wt,
                  __hip_bfloat16* __restrict__ W1t,
                  __hip_bfloat16* __restrict__ W2t,
                  __hip_bfloat16* __restrict__ Wtt)
{
    int i = blockIdx.x * blockDim.x + threadIdx.x;
    int stride = gridDim.x * blockDim.x;
    for (int x = i; x < 256 * 512; x += stride) {        // W1t[n][k] = W1[k][n]
        int n = x >> 9, k = x & 511;
        W1t[x] = __float2bfloat16(W1[k * 256 + n]);
    }
    for (int x = i; x < 64 * 256; x += stride) {         // W2t[n][k] = W2[k][n]
        int n = x >> 8, k = x & 255;
        W2t[x] = __float2bfloat16(W2[k * 64 + n]);
    }
    for (int x = i; x < 256 * FSTR; x += stride) {       // Wtt[n][k], pad k>=389
        int n = x / FSTR, k = x - n * FSTR;
        float v = (k < KREAL) ? Wt[k * 256 + n] : 0.f;
        Wtt[x] = __float2bfloat16(v);
    }
}

// ----------------------------------------------------------------- mlp0 ----
// X1b = bf16(relu(D @ W0 + b0)), D: B x 13, W0: 13 x 512.
__global__ __launch_bounds__(512)
void mlp0_kernel(const float* __restrict__ D, const float* __restrict__ W0,
                 const float* __restrict__ b0, __hip_bfloat16* __restrict__ X1)
{
    __shared__ float w[NDENSE * 512];
    __shared__ float bb[512];
    __shared__ float drow[8][NDENSE];

    int tid = threadIdx.x;
    for (int i = tid; i < NDENSE * 512; i += 512) w[i] = W0[i];
    bb[tid] = b0[tid];
    int rbase = blockIdx.x * 8;
    if (tid < 8 * NDENSE)
        drow[tid / NDENSE][tid % NDENSE] =
            D[(size_t)(rbase + tid / NDENSE) * NDENSE + tid % NDENSE];
    __syncthreads();

    int j = tid;
    for (int r = 0; r < 8; ++r) {
        float acc = bb[j];
        #pragma unroll
        for (int k = 0; k < NDENSE; ++k) acc += drow[r][k] * w[k * 512 + j];
        X1[(size_t)(rbase + r) * 512 + j] = __float2bfloat16(fmaxf(acc, 0.f));
    }
}

// -------------------------------------------------- bf16 MFMA NT GEMM ----
// C[M x N] = act(A[M x K] @ Bt[N x K]^T + bias). BK=32, 256 thr = 4 waves.
template<int BM, int BN, int WM, int WN, bool RELU, bool OUT_BF16>
__global__ __launch_bounds__(256)
void gemm_nt_bf16(const __hip_bfloat16* __restrict__ A, int lda,
                  const __hip_bfloat16* __restrict__ Bt, int ldb,
                  const float* __restrict__ bias,
                  void* __restrict__ C, int ldc, int K)
{
    static_assert((BM / WM) * (BN / WN) == 4, "4 waves");
    constexpr int AR = (BM * 4) / 256;   // staging rounds for A (4 chunks/row)
    constexpr int BR = (BN * 4) / 256;
    constexpr int NWC = BN / WN;

    __shared__ __align__(16) short Alds[BM * 32];
    __shared__ __align__(16) short Blds[BN * 32];

    int tid = threadIdx.x;
    int w = tid >> 6, lane = tid & 63;
    int wr = w / NWC, wc = w % NWC;
    int lr = lane & 15, lg = lane >> 4;
    int m0 = blockIdx.x * BM;
    int n0 = blockIdx.y * BN;

    f32x4 acc[WM / 16][WN / 16] = {};

    for (int k0 = 0; k0 < K; k0 += 32) {
        #pragma unroll
        for (int rd = 0; rd < AR; ++rd) {
            int c = rd * 256 + tid;
            int row = c >> 2, kc = c & 3;
            gload_lds16(A + (size_t)(m0 + row) * lda + k0 + kc * 8, &Alds[c * 8]);
        }
        #pragma unroll
        for (int rd = 0; rd < BR; ++rd) {
            int c = rd * 256 + tid;
            int row = c >> 2, kc = c & 3;
            gload_lds16(Bt + (size_t)(n0 + row) * ldb + k0 + kc * 8, &Blds[c * 8]);
        }
        __syncthreads();

        bf16x8 a[WM / 16], b[WN / 16];
        #pragma unroll
        for (int mi = 0; mi < WM / 16; ++mi)
            a[mi] = *(const bf16x8*)&Alds[(wr * WM + mi * 16 + lr) * 32 + lg * 8];
        #pragma unroll
        for (int ni = 0; ni < WN / 16; ++ni)
            b[ni] = *(const bf16x8*)&Blds[(wc * WN + ni * 16 + lr) * 32 + lg * 8];
        #pragma unroll
        for (int mi = 0; mi < WM / 16; ++mi)
            #pragma unroll
            for (int ni = 0; ni < WN / 16; ++ni)
                acc[mi][ni] = __builtin_amdgcn_mfma_f32_16x16x32_bf16(
                    a[mi], b[ni], acc[mi][ni], 0, 0, 0);
        __syncthreads();
    }

    #pragma unroll
    for (int ni = 0; ni < WN / 16; ++ni) {
        int col = n0 + wc * WN + ni * 16 + lr;
        float bv = bias[col];
        #pragma unroll
        for (int mi = 0; mi < WM / 16; ++mi) {
            f32x4 v = acc[mi][ni];
            #pragma unroll
            for (int r = 0; r < 4; ++r) {
                int row = m0 + wr * WM + mi * 16 + lg * 4 + r;
                float x = v[r] + bv;
                if (RELU) x = fmaxf(x, 0.f);
                if (OUT_BF16)
                    ((__hip_bfloat16*)C)[(size_t)row * ldc + col] = __float2bfloat16(x);
                else
                    ((float*)C)[(size_t)row * ldc + col] = x;
            }
        }
    }
}

// ------------------------------------------------------------ interact ----
// One block (256 thr) per sample: gather 26 emb rows to LDS (f32), 325 pair
// dots -> bf16 feat[s][64+p]; zero pad cols 389..415.
#define ESTR 66

__global__ __launch_bounds__(256)
void interact_kernel(const int* __restrict__ sparse,
                     const float* __restrict__ tables,
                     __hip_bfloat16* __restrict__ feat)
{
    __shared__ float e[NSPARSE * ESTR];

    int s = blockIdx.x;
    int tid = threadIdx.x;
    int wv = tid >> 6;
    int lane = tid & 63;

    for (int i = wv; i < NSPARSE; i += 4) {
        int idx = sparse[s * NSPARSE + i];   // wave-uniform
        e[i * ESTR + lane] = tables[((long)i * VOCAB + idx) * EMB + lane];
    }
    __syncthreads();

    for (int p = tid; p < 325; p += 256) {
        int pi = p, i = 0;
        while (pi >= (NSPARSE - 1) - i) { pi -= (NSPARSE - 1) - i; ++i; }
        int j = i + 1 + pi;
        const float* ei = &e[i * ESTR];
        const float* ej = &e[j * ESTR];
        float acc = 0.f;
        #pragma unroll
        for (int d = 0; d < EMB; d += 2) {
            float2 a = *(const float2*)(ei + d);
            float2 b = *(const float2*)(ej + d);
            acc += a.x * b.x + a.y * b.y;
        }
        feat[(size_t)s * FSTR + 64 + p] = __float2bfloat16(acc);
    }
    if (tid < FSTR - KREAL)
        feat[(size_t)s * FSTR + KREAL + tid] = __float2bfloat16(0.f);
}

// -------------------------------------------------------------- launch ----
extern "C" void kernel_launch(void* const* d_in, const int* in_sizes, int n_in,
                              void* d_out, int out_size, void* d_ws, size_t ws_size,
                              hipStream_t stream)
{
    const float* dense  = (const float*)d_in[0];
    const int*   sparse = (const int*)  d_in[1];
    const float* tables = (const float*)d_in[2];
    const float* W0     = (const float*)d_in[3];
    const float* b0     = (const float*)d_in[4];
    const float* W1     = (const float*)d_in[5];
    const float* b1     = (const float*)d_in[6];
    const float* W2     = (const float*)d_in[7];
    const float* b2     = (const float*)d_in[8];
    const float* Wt     = (const float*)d_in[9];
    const float* bt     = (const float*)d_in[10];
    float* out = (float*)d_out;

    char* ws = (char*)d_ws;
    __hip_bfloat16* X1b   = (__hip_bfloat16*)(ws);
    __hip_bfloat16* X2b   = (__hip_bfloat16*)(ws + 16777216);
    __hip_bfloat16* featb = (__hip_bfloat16*)(ws + 25165824);
    __hip_bfloat16* W1t   = (__hip_bfloat16*)(ws + 38797312);
    __hip_bfloat16* W2t   = (__hip_bfloat16*)(ws + 39059456);
    __hip_bfloat16* Wtt   = (__hip_bfloat16*)(ws + 39092224);

    // 0) weight convert + transpose
    prep_weights<<<256, 256, 0, stream>>>(W1, W2, Wt, W1t, W2t, Wtt);

    // 1) X1b = bf16(relu(D @ W0 + b0))
    mlp0_kernel<<<BATCH / 8, 512, 0, stream>>>(dense, W0, b0, X1b);

    // 2) X2b = bf16(relu(X1b @ W1 + b1))  M=16384 N=256 K=512
    {
        dim3 g(BATCH / 128, 256 / 128);
        gemm_nt_bf16<128, 128, 64, 64, true, true><<<g, 256, 0, stream>>>(
            X1b, 512, W1t, 512, b1, X2b, 256, 512);
    }

    // 3) featb[:,0:64] = bf16(relu(X2b @ W2 + b2))  M=16384 N=64 K=256
    {
        dim3 g(BATCH / 128, 1);
        gemm_nt_bf16<128, 64, 32, 64, true, true><<<g, 256, 0, stream>>>(
            X2b, 256, W2t, 256, b2, featb, FSTR, 256);
    }

    // 4) featb[:,64:389] = pair dots; featb[:,389:416] = 0
    interact_kernel<<<BATCH, 256, 0, stream>>>(sparse, tables, featb);

    // 5) out = featb @ Wt + bt  M=16384 N=256 K=416 (f32 out)
    {
        dim3 g(BATCH / 128, 256 / 128);
        gemm_nt_bf16<128, 128, 64, 64, false, false><<<g, 256, 0, stream>>>(
            featb, FSTR, Wtt, FSTR, bt, out, 256, FSTR);
    }
}

// Round 3
// 77.236 us; speedup vs baseline: 2.9058x; 1.6622x over previous
//
#include <hip/hip_runtime.h>
#include <hip/hip_bf16.h>

// DLRM-like, bf16-MFMA version, round 3.
// B=16384; dense 13 -> [512,256,64]; 26 x emb64 gather; 325 pair dots via
// 32x32x16 MFMA gram; top GEMM (389 -> 256, K padded to 416).
//
// ws layout (bytes):
//   [0,          16777216)  X1b   16384x512 bf16
//   [16777216,   25165824)  X2b   16384x256 bf16
//   [25165824,   38797312)  featb 16384x416 bf16
//   [38797312,   39059456)  W1t   256x512  bf16
//   [39059456,   39092224)  W2t   64x256   bf16
//   [39092224,   39305216)  Wtt   256x416  bf16 (k>=389 zero)

#define BATCH     16384
#define NDENSE    13
#define NSPARSE   26
#define VOCAB     100000
#define EMB       64
#define FSTR      416    // 64 dense + 325 interact + 27 zero pad (mult of 32)
#define KREAL     389

typedef __attribute__((ext_vector_type(8)))  short bf16x8;
typedef __attribute__((ext_vector_type(4)))  float f32x4;
typedef __attribute__((ext_vector_type(16))) float f32x16;

__device__ inline void gload_lds16(const void* g, void* l) {
    __builtin_amdgcn_global_load_lds(
        (const __attribute__((address_space(1))) void*)g,
        (__attribute__((address_space(3))) void*)l, 16, 0, 0);
}

__device__ inline short f2bf(float x) {
    __hip_bfloat16 h = __float2bfloat16(x);
    return *reinterpret_cast<short*>(&h);
}

// ----------------------------------------------------------------- prep ----
__global__ __launch_bounds__(256)
void prep_weights(const float* __restrict__ W1, const float* __restrict__ W2,
                  const float* __restrict__ Wt,
                  __hip_bfloat16* __restrict__ W1t,
                  __hip_bfloat16* __restrict__ W2t,
                  __hip_bfloat16* __restrict__ Wtt)
{
    int i = blockIdx.x * blockDim.x + threadIdx.x;
    int stride = gridDim.x * blockDim.x;
    for (int x = i; x < 256 * 512; x += stride) {        // W1t[n][k] = W1[k][n]
        int n = x >> 9, k = x & 511;
        W1t[x] = __float2bfloat16(W1[k * 256 + n]);
    }
    for (int x = i; x < 64 * 256; x += stride) {         // W2t[n][k] = W2[k][n]
        int n = x >> 8, k = x & 255;
        W2t[x] = __float2bfloat16(W2[k * 64 + n]);
    }
    for (int x = i; x < 256 * FSTR; x += stride) {       // Wtt[n][k], pad k>=389
        int n = x / FSTR, k = x - n * FSTR;
        float v = (k < KREAL) ? Wt[k * 256 + n] : 0.f;
        Wtt[x] = __float2bfloat16(v);
    }
}

// ----------------------------------------------------------------- mlp0 ----
__global__ __launch_bounds__(512)
void mlp0_kernel(const float* __restrict__ D, const float* __restrict__ W0,
                 const float* __restrict__ b0, __hip_bfloat16* __restrict__ X1)
{
    __shared__ float w[NDENSE * 512];
    __shared__ float bb[512];
    __shared__ float drow[8][NDENSE];

    int tid = threadIdx.x;
    for (int i = tid; i < NDENSE * 512; i += 512) w[i] = W0[i];
    bb[tid] = b0[tid];
    int rbase = blockIdx.x * 8;
    if (tid < 8 * NDENSE)
        drow[tid / NDENSE][tid % NDENSE] =
            D[(size_t)(rbase + tid / NDENSE) * NDENSE + tid % NDENSE];
    __syncthreads();

    int j = tid;
    for (int r = 0; r < 8; ++r) {
        float acc = bb[j];
        #pragma unroll
        for (int k = 0; k < NDENSE; ++k) acc += drow[r][k] * w[k * 512 + j];
        X1[(size_t)(rbase + r) * 512 + j] = __float2bfloat16(fmaxf(acc, 0.f));
    }
}

// -------------------------------------------------- bf16 MFMA NT GEMM ----
// C[M x N] = act(A[M x K] @ Bt[N x K]^T + bias). BK=32, 256 thr = 4 waves.
template<int BM, int BN, int WM, int WN, bool RELU, bool OUT_BF16>
__global__ __launch_bounds__(256)
void gemm_nt_bf16(const __hip_bfloat16* __restrict__ A, int lda,
                  const __hip_bfloat16* __restrict__ Bt, int ldb,
                  const float* __restrict__ bias,
                  void* __restrict__ C, int ldc, int K)
{
    static_assert((BM / WM) * (BN / WN) == 4, "4 waves");
    constexpr int AR = (BM * 4) / 256;
    constexpr int BR = (BN * 4) / 256;
    constexpr int NWC = BN / WN;

    __shared__ __align__(16) short Alds[BM * 32];
    __shared__ __align__(16) short Blds[BN * 32];

    int tid = threadIdx.x;
    int w = tid >> 6, lane = tid & 63;
    int wr = w / NWC, wc = w % NWC;
    int lr = lane & 15, lg = lane >> 4;
    int m0 = blockIdx.x * BM;
    int n0 = blockIdx.y * BN;

    f32x4 acc[WM / 16][WN / 16] = {};

    for (int k0 = 0; k0 < K; k0 += 32) {
        #pragma unroll
        for (int rd = 0; rd < AR; ++rd) {
            int c = rd * 256 + tid;
            int row = c >> 2, kc = c & 3;
            gload_lds16(A + (size_t)(m0 + row) * lda + k0 + kc * 8, &Alds[c * 8]);
        }
        #pragma unroll
        for (int rd = 0; rd < BR; ++rd) {
            int c = rd * 256 + tid;
            int row = c >> 2, kc = c & 3;
            gload_lds16(Bt + (size_t)(n0 + row) * ldb + k0 + kc * 8, &Blds[c * 8]);
        }
        __syncthreads();

        bf16x8 a[WM / 16], b[WN / 16];
        #pragma unroll
        for (int mi = 0; mi < WM / 16; ++mi)
            a[mi] = *(const bf16x8*)&Alds[(wr * WM + mi * 16 + lr) * 32 + lg * 8];
        #pragma unroll
        for (int ni = 0; ni < WN / 16; ++ni)
            b[ni] = *(const bf16x8*)&Blds[(wc * WN + ni * 16 + lr) * 32 + lg * 8];
        #pragma unroll
        for (int mi = 0; mi < WM / 16; ++mi)
            #pragma unroll
            for (int ni = 0; ni < WN / 16; ++ni)
                acc[mi][ni] = __builtin_amdgcn_mfma_f32_16x16x32_bf16(
                    a[mi], b[ni], acc[mi][ni], 0, 0, 0);
        __syncthreads();
    }

    #pragma unroll
    for (int ni = 0; ni < WN / 16; ++ni) {
        int col = n0 + wc * WN + ni * 16 + lr;
        float bv = bias[col];
        #pragma unroll
        for (int mi = 0; mi < WM / 16; ++mi) {
            f32x4 v = acc[mi][ni];
            #pragma unroll
            for (int r = 0; r < 4; ++r) {
                int row = m0 + wr * WM + mi * 16 + lg * 4 + r;
                float x = v[r] + bv;
                if (RELU) x = fmaxf(x, 0.f);
                if (OUT_BF16)
                    ((__hip_bfloat16*)C)[(size_t)row * ldc + col] = __float2bfloat16(x);
                else
                    ((float*)C)[(size_t)row * ldc + col] = x;
            }
        }
    }
}

// ------------------------------------------------------------ interact ----
// One wave per sample: gather embedding fragments straight from tables,
// gram = E E^T via 4x mfma_f32_32x32x16_bf16 (A frag == B frag), scatter
// upper triangle to LDS stage, coalesced float4 write of cols 64..415.
__global__ __launch_bounds__(256)
void interact_mfma(const int* __restrict__ sparse,
                   const float* __restrict__ tables,
                   __hip_bfloat16* __restrict__ feat)
{
    __shared__ __align__(16) unsigned short stage[4][352];

    int w = threadIdx.x >> 6, lane = threadIdx.x & 63;
    int s = blockIdx.x * 4 + w;
    int row = lane & 31;
    int half = lane >> 5;
    bool valid = row < NSPARSE;
    int srow = valid ? row : 0;
    int idx = sparse[s * NSPARSE + srow];
    const float* rp = tables + ((long)srow * VOCAB + idx) * EMB + half * 8;

    // load the full row fragment set: 8 x float4 (32B per k-step)
    float4 La[4], Lb[4];
    #pragma unroll
    for (int t = 0; t < 4; ++t) {
        La[t] = *(const float4*)(rp + t * 16);
        Lb[t] = *(const float4*)(rp + t * 16 + 4);
    }

    f32x16 acc = {};
    #pragma unroll
    for (int t = 0; t < 4; ++t) {
        bf16x8 f;
        float va[8] = {La[t].x, La[t].y, La[t].z, La[t].w,
                       Lb[t].x, Lb[t].y, Lb[t].z, Lb[t].w};
        #pragma unroll
        for (int j = 0; j < 8; ++j) f[j] = f2bf(valid ? va[j] : 0.f);
        acc = __builtin_amdgcn_mfma_f32_32x32x16_bf16(f, f, acc, 0, 0, 0);
    }

    // zero the pad region (feature cols 389..415 -> stage idx 325..351)
    if (lane < 27) stage[w][325 + lane] = 0;

    // scatter upper triangle: C layout col=lane&31, row=(reg&3)+8*(reg>>2)+4*half
    int c = row;
    if (c < NSPARSE) {
        #pragma unroll
        for (int reg = 0; reg < 16; ++reg) {
            int r = (reg & 3) + 8 * (reg >> 2) + 4 * half;
            if (r < c) {
                int p = r * (2 * NSPARSE - r - 1) / 2 + (c - r - 1);
                stage[w][p] = (unsigned short)f2bf(acc[reg]);
            }
        }
    }
    __syncthreads();

    // coalesced write: 352 bf16 = 704B = 44 lanes x 16B
    if (lane < 44) {
        const float4* sp = reinterpret_cast<const float4*>(stage[w]);
        *(float4*)(feat + (size_t)s * FSTR + 64 + lane * 8) = sp[lane];
    }
}

// -------------------------------------------------------------- launch ----
extern "C" void kernel_launch(void* const* d_in, const int* in_sizes, int n_in,
                              void* d_out, int out_size, void* d_ws, size_t ws_size,
                              hipStream_t stream)
{
    const float* dense  = (const float*)d_in[0];
    const int*   sparse = (const int*)  d_in[1];
    const float* tables = (const float*)d_in[2];
    const float* W0     = (const float*)d_in[3];
    const float* b0     = (const float*)d_in[4];
    const float* W1     = (const float*)d_in[5];
    const float* b1     = (const float*)d_in[6];
    const float* W2     = (const float*)d_in[7];
    const float* b2     = (const float*)d_in[8];
    const float* Wt     = (const float*)d_in[9];
    const float* bt     = (const float*)d_in[10];
    float* out = (float*)d_out;

    char* ws = (char*)d_ws;
    __hip_bfloat16* X1b   = (__hip_bfloat16*)(ws);
    __hip_bfloat16* X2b   = (__hip_bfloat16*)(ws + 16777216);
    __hip_bfloat16* featb = (__hip_bfloat16*)(ws + 25165824);
    __hip_bfloat16* W1t   = (__hip_bfloat16*)(ws + 38797312);
    __hip_bfloat16* W2t   = (__hip_bfloat16*)(ws + 39059456);
    __hip_bfloat16* Wtt   = (__hip_bfloat16*)(ws + 39092224);

    prep_weights<<<256, 256, 0, stream>>>(W1, W2, Wt, W1t, W2t, Wtt);

    mlp0_kernel<<<BATCH / 8, 512, 0, stream>>>(dense, W0, b0, X1b);

    // mlp1: M=16384 N=256 K=512, 64x128 tiles -> 512 blocks
    {
        dim3 g(BATCH / 64, 256 / 128);
        gemm_nt_bf16<64, 128, 32, 64, true, true><<<g, 256, 0, stream>>>(
            X1b, 512, W1t, 512, b1, X2b, 256, 512);
    }

    // mlp2: M=16384 N=64 K=256, 64x64 tiles -> 256 blocks
    {
        dim3 g(BATCH / 64, 1);
        gemm_nt_bf16<64, 64, 32, 32, true, true><<<g, 256, 0, stream>>>(
            X2b, 256, W2t, 256, b2, featb, FSTR, 256);
    }

    // interact: 1 wave/sample, 4 samples/block -> 4096 blocks
    interact_mfma<<<BATCH / 4, 256, 0, stream>>>(sparse, tables, featb);

    // top: M=16384 N=256 K=416, 64x128 tiles -> 512 blocks
    {
        dim3 g(BATCH / 64, 256 / 128);
        gemm_nt_bf16<64, 128, 32, 64, false, false><<<g, 256, 0, stream>>>(
            featb, FSTR, Wtt, FSTR, bt, out, 256, FSTR);
    }
}

// Round 4
// 60.832 us; speedup vs baseline: 3.6894x; 1.2697x over previous
//
#include <hip/hip_runtime.h>
#include <hip/hip_bf16.h>

// DLRM-like, round 4: 3-kernel fused pipeline.
//   prep:         weights -> bf16 NT (W0t padded K13->32, Wtt padded K389->416)
//   fused_mlp:    dense -> relu MLP chain entirely in LDS -> featbD (16384x64 bf16)
//   interact_top: gather+gram straight into LDS A-tile + top GEMM -> out
//
// ws layout (bytes):
//   [0,       2097152)  featbD 16384x64 bf16
//   [2097152, 2129920)  W0t  512x32  bf16 (k>=13 zero)
//   [2129920, 2392064)  W1t  256x512 bf16
//   [2392064, 2424832)  W2t  64x256  bf16
//   [2424832, 2637824)  Wtt  256x416 bf16 (k>=389 zero)

#define BATCH   16384
#define NSPARSE 26
#define VOCAB   100000
#define EMB     64
#define KTOP    416
#define KREAL   389
#define ASTR    424   // interact A-tile row stride (848B: 212 dw % 32 = 20 -> 2-way)
#define X1STR   520   // 1040B: 260 dw % 32 = 4 -> conflict-free frag reads
#define X2STR   264   // 528B:  132 dw % 32 = 4

typedef __attribute__((ext_vector_type(8)))  short bf16x8;
typedef __attribute__((ext_vector_type(4)))  float f32x4;
typedef __attribute__((ext_vector_type(16))) float f32x16;

__device__ inline void gload_lds16(const void* g, void* l) {
    __builtin_amdgcn_global_load_lds(
        (const __attribute__((address_space(1))) void*)g,
        (__attribute__((address_space(3))) void*)l, 16, 0, 0);
}

__device__ inline short f2bf(float x) {
    __hip_bfloat16 h = __float2bfloat16(x);
    return *reinterpret_cast<short*>(&h);
}

// ----------------------------------------------------------------- prep ----
__global__ __launch_bounds__(256)
void prep_weights(const float* __restrict__ W0, const float* __restrict__ W1,
                  const float* __restrict__ W2, const float* __restrict__ Wt,
                  short* __restrict__ W0t, short* __restrict__ W1t,
                  short* __restrict__ W2t, short* __restrict__ Wtt)
{
    int i = blockIdx.x * blockDim.x + threadIdx.x;
    int stride = gridDim.x * blockDim.x;
    for (int x = i; x < 512 * 32; x += stride) {        // W0t[n][k], pad k>=13
        int n = x >> 5, k = x & 31;
        W0t[x] = f2bf(k < 13 ? W0[k * 512 + n] : 0.f);
    }
    for (int x = i; x < 256 * 512; x += stride) {       // W1t[n][k]
        int n = x >> 9, k = x & 511;
        W1t[x] = f2bf(W1[k * 256 + n]);
    }
    for (int x = i; x < 64 * 256; x += stride) {        // W2t[n][k]
        int n = x >> 8, k = x & 255;
        W2t[x] = f2bf(W2[k * 64 + n]);
    }
    for (int x = i; x < 256 * KTOP; x += stride) {      // Wtt[n][k], pad k>=389
        int n = x / KTOP, k = x - n * KTOP;
        Wtt[x] = f2bf(k < KREAL ? Wt[k * 256 + n] : 0.f);
    }
}

// ------------------------------------------------------------ fused MLP ----
// 64 rows/block, 256 blocks. All intermediates in LDS (118KB -> 1 block/CU).
__global__ __launch_bounds__(256)
void fused_mlp(const float* __restrict__ D, const short* __restrict__ W0t,
               const float* __restrict__ b0,
               const short* __restrict__ W1t, const float* __restrict__ b1,
               const short* __restrict__ W2t, const float* __restrict__ b2,
               short* __restrict__ featbD)
{
    __shared__ __align__(16) short Ds[64 * 32];        // 4KB
    __shared__ __align__(16) short X1s[64 * X1STR];    // 66.5KB
    __shared__ __align__(16) short X2s[64 * X2STR];    // 33.8KB
    __shared__ __align__(16) short Bst[256 * 32];      // 16KB

    int tid = threadIdx.x;
    int w = tid >> 6, lane = tid & 63;
    int lr = lane & 15, lg = lane >> 4;
    int wr = w >> 1, wc = w & 1;
    int rbase = blockIdx.x * 64;

    // stage D (64x13 f32) -> Ds bf16 padded to K=32
    for (int x = tid; x < 64 * 32; x += 256) {
        int r = x >> 5, k = x & 31;
        Ds[x] = (k < 13) ? f2bf(D[(size_t)(rbase + r) * 13 + k]) : (short)0;
    }
    __syncthreads();

    // phase 0: X1 = relu(D @ W0 + b0). out 64x512; wave -> 32x256; K=32 (1 step)
    {
        bf16x8 a[2];
        #pragma unroll
        for (int mi = 0; mi < 2; ++mi)
            a[mi] = *(const bf16x8*)&Ds[(wr * 32 + mi * 16 + lr) * 32 + lg * 8];
        f32x4 acc[2][16] = {};
        #pragma unroll
        for (int ni = 0; ni < 16; ++ni) {
            bf16x8 b = *(const bf16x8*)(W0t + (wc * 256 + ni * 16 + lr) * 32 + lg * 8);
            #pragma unroll
            for (int mi = 0; mi < 2; ++mi)
                acc[mi][ni] = __builtin_amdgcn_mfma_f32_16x16x32_bf16(
                    a[mi], b, acc[mi][ni], 0, 0, 0);
        }
        #pragma unroll
        for (int ni = 0; ni < 16; ++ni) {
            int col = wc * 256 + ni * 16 + lr;
            float bv = b0[col];
            #pragma unroll
            for (int mi = 0; mi < 2; ++mi)
                #pragma unroll
                for (int j = 0; j < 4; ++j) {
                    int r = wr * 32 + mi * 16 + lg * 4 + j;
                    X1s[r * X1STR + col] = f2bf(fmaxf(acc[mi][ni][j] + bv, 0.f));
                }
        }
    }
    __syncthreads();

    // phase 1: X2 = relu(X1 @ W1 + b1). K=512 (16 steps); wave -> 32x128
    {
        f32x4 acc[2][8] = {};
        for (int k0 = 0; k0 < 512; k0 += 32) {
            #pragma unroll
            for (int rd = 0; rd < 4; ++rd) {
                int slot = rd * 256 + tid;
                int n = slot >> 2, kc = slot & 3;
                gload_lds16(W1t + (size_t)n * 512 + k0 + kc * 8, &Bst[slot * 8]);
            }
            __syncthreads();
            bf16x8 a[2];
            #pragma unroll
            for (int mi = 0; mi < 2; ++mi)
                a[mi] = *(const bf16x8*)&X1s[(wr * 32 + mi * 16 + lr) * X1STR + k0 + lg * 8];
            #pragma unroll
            for (int ni = 0; ni < 8; ++ni) {
                bf16x8 b = *(const bf16x8*)&Bst[(wc * 128 + ni * 16 + lr) * 32 + lg * 8];
                #pragma unroll
                for (int mi = 0; mi < 2; ++mi)
                    acc[mi][ni] = __builtin_amdgcn_mfma_f32_16x16x32_bf16(
                        a[mi], b, acc[mi][ni], 0, 0, 0);
            }
            __syncthreads();
        }
        #pragma unroll
        for (int ni = 0; ni < 8; ++ni) {
            int col = wc * 128 + ni * 16 + lr;
            float bv = b1[col];
            #pragma unroll
            for (int mi = 0; mi < 2; ++mi)
                #pragma unroll
                for (int j = 0; j < 4; ++j) {
                    int r = wr * 32 + mi * 16 + lg * 4 + j;
                    X2s[r * X2STR + col] = f2bf(fmaxf(acc[mi][ni][j] + bv, 0.f));
                }
        }
    }
    __syncthreads();

    // phase 2: dense_out = relu(X2 @ W2 + b2). K=256 (8 steps); wave -> 32x32
    {
        f32x4 acc[2][2] = {};
        for (int k0 = 0; k0 < 256; k0 += 32) {
            {
                int n = tid >> 2, kc = tid & 3;   // 256 slots = 64n x 4kc
                gload_lds16(W2t + (size_t)n * 256 + k0 + kc * 8, &Bst[tid * 8]);
            }
            __syncthreads();
            bf16x8 a[2];
            #pragma unroll
            for (int mi = 0; mi < 2; ++mi)
                a[mi] = *(const bf16x8*)&X2s[(wr * 32 + mi * 16 + lr) * X2STR + k0 + lg * 8];
            #pragma unroll
            for (int ni = 0; ni < 2; ++ni) {
                bf16x8 b = *(const bf16x8*)&Bst[(wc * 32 + ni * 16 + lr) * 32 + lg * 8];
                #pragma unroll
                for (int mi = 0; mi < 2; ++mi)
                    acc[mi][ni] = __builtin_amdgcn_mfma_f32_16x16x32_bf16(
                        a[mi], b, acc[mi][ni], 0, 0, 0);
            }
            __syncthreads();
        }
        #pragma unroll
        for (int ni = 0; ni < 2; ++ni) {
            int col = wc * 32 + ni * 16 + lr;
            float bv = b2[col];
            #pragma unroll
            for (int mi = 0; mi < 2; ++mi)
                #pragma unroll
                for (int j = 0; j < 4; ++j) {
                    int r = wr * 32 + mi * 16 + lg * 4 + j;
                    featbD[(size_t)(rbase + r) * 64 + col] =
                        f2bf(fmaxf(acc[mi][ni][j] + bv, 0.f));
                }
        }
    }
}

// -------------------------------------------------------- interact + top ----
// 32 samples/block, 512 blocks (2/CU). Gram built directly in LDS A-tile,
// then top GEMM K=416 -> out (f32).
__global__ __launch_bounds__(256)
void interact_top(const int* __restrict__ sparse, const float* __restrict__ tables,
                  const short* __restrict__ featbD, const short* __restrict__ Wtt,
                  const float* __restrict__ bt, float* __restrict__ out)
{
    __shared__ __align__(16) short As[32 * ASTR];     // 26.5KB
    __shared__ __align__(16) short Wst[256 * 32];     // 16KB

    int tid = threadIdx.x;
    int w = tid >> 6, lane = tid & 63;
    int lr = lane & 15, lg = lane >> 4;
    int wr = w >> 1, wc = w & 1;
    int sbase = blockIdx.x * 32;

    // (a) dense cols 0..63 <- featbD; zero pad cols 389..415
    {
        int r = tid >> 3, seg = tid & 7;
        bf16x8 v = *(const bf16x8*)(featbD + (size_t)(sbase + r) * 64 + seg * 8);
        *(bf16x8*)&As[r * ASTR + seg * 8] = v;
    }
    for (int x = tid; x < 32 * 27; x += 256) {
        int r = x / 27, c = x - r * 27;
        As[r * ASTR + KREAL + c] = 0;
    }

    // (b) gram: wave w -> local samples w*8 .. w*8+7, 32x32x16 MFMA, A==B
    {
        int row = lane & 31, half = lane >> 5;
        bool valid = row < NSPARSE;
        int srow = valid ? row : 0;
        #pragma unroll
        for (int li = 0; li < 8; ++li) {
            int s = sbase + w * 8 + li;
            int idx = sparse[s * NSPARSE + srow];
            const float* rp = tables + ((long)srow * VOCAB + idx) * EMB + half * 8;
            f32x16 acc = {};
            #pragma unroll
            for (int t = 0; t < 4; ++t) {
                float4 La = *(const float4*)(rp + t * 16);
                float4 Lb = *(const float4*)(rp + t * 16 + 4);
                float va[8] = {La.x, La.y, La.z, La.w, Lb.x, Lb.y, Lb.z, Lb.w};
                bf16x8 f;
                #pragma unroll
                for (int jj = 0; jj < 8; ++jj) f[jj] = f2bf(valid ? va[jj] : 0.f);
                acc = __builtin_amdgcn_mfma_f32_32x32x16_bf16(f, f, acc, 0, 0, 0);
            }
            int c = row;
            if (c < NSPARSE) {
                #pragma unroll
                for (int reg = 0; reg < 16; ++reg) {
                    int r = (reg & 3) + 8 * (reg >> 2) + 4 * half;
                    if (r < c) {
                        int p = r * (2 * NSPARSE - r - 1) / 2 + (c - r - 1);
                        As[(w * 8 + li) * ASTR + 64 + p] = f2bf(acc[reg]);
                    }
                }
            }
        }
    }
    __syncthreads();

    // (c) top GEMM: out32x256 = As(32xK416) @ Wtt^T; wave -> 16x128
    f32x4 acc[8] = {};
    for (int k0 = 0; k0 < KTOP; k0 += 32) {
        #pragma unroll
        for (int rd = 0; rd < 4; ++rd) {
            int slot = rd * 256 + tid;
            int n = slot >> 2, kc = slot & 3;
            gload_lds16(Wtt + (size_t)n * KTOP + k0 + kc * 8, &Wst[slot * 8]);
        }
        __syncthreads();
        bf16x8 a = *(const bf16x8*)&As[(wr * 16 + lr) * ASTR + k0 + lg * 8];
        #pragma unroll
        for (int ni = 0; ni < 8; ++ni) {
            bf16x8 b = *(const bf16x8*)&Wst[(wc * 128 + ni * 16 + lr) * 32 + lg * 8];
            acc[ni] = __builtin_amdgcn_mfma_f32_16x16x32_bf16(a, b, acc[ni], 0, 0, 0);
        }
        __syncthreads();
    }

    // (d) epilogue: + bt, f32 out
    #pragma unroll
    for (int ni = 0; ni < 8; ++ni) {
        int col = wc * 128 + ni * 16 + lr;
        float bv = bt[col];
        #pragma unroll
        for (int j = 0; j < 4; ++j) {
            int r = wr * 16 + lg * 4 + j;
            out[(size_t)(sbase + r) * 256 + col] = acc[ni][j] + bv;
        }
    }
}

// -------------------------------------------------------------- launch ----
extern "C" void kernel_launch(void* const* d_in, const int* in_sizes, int n_in,
                              void* d_out, int out_size, void* d_ws, size_t ws_size,
                              hipStream_t stream)
{
    const float* dense  = (const float*)d_in[0];
    const int*   sparse = (const int*)  d_in[1];
    const float* tables = (const float*)d_in[2];
    const float* W0     = (const float*)d_in[3];
    const float* b0     = (const float*)d_in[4];
    const float* W1     = (const float*)d_in[5];
    const float* b1     = (const float*)d_in[6];
    const float* W2     = (const float*)d_in[7];
    const float* b2     = (const float*)d_in[8];
    const float* Wt     = (const float*)d_in[9];
    const float* bt     = (const float*)d_in[10];
    float* out = (float*)d_out;

    char* ws = (char*)d_ws;
    short* featbD = (short*)(ws);
    short* W0t    = (short*)(ws + 2097152);
    short* W1t    = (short*)(ws + 2129920);
    short* W2t    = (short*)(ws + 2392064);
    short* Wtt    = (short*)(ws + 2424832);

    prep_weights<<<256, 256, 0, stream>>>(W0, W1, W2, Wt, W0t, W1t, W2t, Wtt);

    fused_mlp<<<BATCH / 64, 256, 0, stream>>>(dense, W0t, b0, W1t, b1, W2t, b2,
                                              featbD);

    interact_top<<<BATCH / 32, 256, 0, stream>>>(sparse, tables, featbD, Wtt,
                                                 bt, out);
}

// Round 5
// 52.221 us; speedup vs baseline: 4.2978x; 1.1649x over previous
//
#include <hip/hip_runtime.h>
#include <hip/hip_bf16.h>

// DLRM-like, round 5: single fused megakernel (MLP + gram + top GEMM),
// 32 samples/block, 512 blocks, 2 blocks/CU, parity-staggered phase order
// so gather (HBM) overlaps MLP/GEMM (MFMA) across the two resident blocks.
//
// ws layout (bytes):
//   [0,      32768)   W0t 512x32  bf16 (k>=13 zero)
//   [32768,  294912)  W1t 256x512 bf16
//   [294912, 327680)  W2t 64x256  bf16
//   [327680, 540672)  Wtt 256x416 bf16 (k>=389 zero)

#define BATCH   16384
#define NSPARSE 26
#define VOCAB   100000
#define EMB     64
#define KTOP    416
#define KREAL   389
#define SPB     32
#define ASTR    424   // shorts; 212 dw % 32 = 20 -> <=2-way on frag reads
#define X1STR   520   // 260 dw % 32 = 4  -> <=2-way
#define X2STR   264   // 132 dw % 32 = 4  -> <=2-way

typedef __attribute__((ext_vector_type(8)))  short bf16x8;
typedef __attribute__((ext_vector_type(4)))  short s16x4;
typedef __attribute__((ext_vector_type(4)))  float f32x4;
typedef __attribute__((ext_vector_type(16))) float f32x16;

__device__ inline void gload_lds16(const void* g, void* l) {
    __builtin_amdgcn_global_load_lds(
        (const __attribute__((address_space(1))) void*)g,
        (__attribute__((address_space(3))) void*)l, 16, 0, 0);
}

__device__ inline short f2bf(float x) {
    __hip_bfloat16 h = __float2bfloat16(x);
    return *reinterpret_cast<short*>(&h);
}

// ------------------------------------------------- prep: tiled transpose ----
// src f32 [K][N] -> dst bf16 [N][Kpad], zero for k>=K. 32x32 tiles via LDS.
__global__ __launch_bounds__(256)
void prep_weights(const float* __restrict__ W0, const float* __restrict__ W1,
                  const float* __restrict__ W2, const float* __restrict__ Wt,
                  short* __restrict__ W0t, short* __restrict__ W1t,
                  short* __restrict__ W2t, short* __restrict__ Wtt)
{
    __shared__ float tile[32][36];
    int b = blockIdx.x, t = threadIdx.x;
    const float* src; short* dst; int K, N, Kpad, k0, n0;
    if (b < 16)        {              src = W0; dst = W0t; K = 13;  N = 512; Kpad = 32;  k0 = 0;           n0 = b * 32; }
    else if (b < 144)  { int i = b - 16;  src = W1; dst = W1t; K = 512; N = 256; Kpad = 512; k0 = (i >> 3) * 32; n0 = (i & 7) * 32; }
    else if (b < 160)  { int i = b - 144; src = W2; dst = W2t; K = 256; N = 64;  Kpad = 256; k0 = (i >> 1) * 32; n0 = (i & 1) * 32; }
    else               { int i = b - 160; src = Wt; dst = Wtt; K = 389; N = 256; Kpad = 416; k0 = (i >> 3) * 32; n0 = (i & 7) * 32; }

    int r = t >> 3, c4 = (t & 7) * 4;
    int gr = k0 + r;
    float4 v = make_float4(0.f, 0.f, 0.f, 0.f);
    if (gr < K) v = *(const float4*)(src + (size_t)gr * N + n0 + c4);
    tile[r][c4 + 0] = v.x; tile[r][c4 + 1] = v.y;
    tile[r][c4 + 2] = v.z; tile[r][c4 + 3] = v.w;
    __syncthreads();
    s16x4 o;
    #pragma unroll
    for (int j = 0; j < 4; ++j) o[j] = f2bf(tile[c4 + j][r]);
    *(s16x4*)&dst[(size_t)(n0 + r) * Kpad + k0 + c4] = o;
}

// ------------------------------------------------------------ megakernel ----
__global__ __launch_bounds__(256, 2)
void fused_all(const int* __restrict__ sparse, const float* __restrict__ tables,
               const float* __restrict__ D,
               const short* __restrict__ W0t, const float* __restrict__ b0,
               const short* __restrict__ W1t, const float* __restrict__ b1,
               const short* __restrict__ W2t, const float* __restrict__ b2,
               const short* __restrict__ Wtt, const float* __restrict__ bt,
               float* __restrict__ out)
{
    // As 27136 | X1s(33280; X2s aliases) | Bst 16384 | Ds 2048 = 78848 B
    __shared__ __align__(16) char smem[78848];
    short* As  = (short*)(smem);
    short* X1s = (short*)(smem + 27136);
    short* X2s = (short*)(smem + 27136);   // alias: X1s dead after phase-1 loop
    short* Bst = (short*)(smem + 60416);
    short* Ds  = (short*)(smem + 76800);

    int tid = threadIdx.x;
    int w = tid >> 6, lane = tid & 63;
    int lr = lane & 15, lg = lane >> 4;
    int wr = w >> 1, wc = w & 1;
    int swz = (lg ^ (lr & 3)) * 8;         // bank-conflict fix for Bst reads
    int sbase = blockIdx.x * SPB;

    // stage Ds (32x13 f32 -> bf16, pad k to 32) + zero As pad cols 389..415
    for (int x = tid; x < SPB * 13; x += 256) {
        int r = x / 13, k = x - r * 13;
        Ds[r * 32 + k] = f2bf(D[(size_t)sbase * 13 + x]);
    }
    for (int x = tid; x < SPB * 19; x += 256) {
        int r = x / 19, k = 13 + (x - r * 19);
        Ds[r * 32 + k] = 0;
    }
    for (int x = tid; x < SPB * 27; x += 256) {
        int r = x / 27, c = x - r * 27;
        As[r * ASTR + KREAL + c] = 0;
    }
    __syncthreads();

    // ---- gram phase: wave w handles samples w*8..w*8+7, 2-deep pipelined ----
    auto gram_phase = [&]() {
        int row = lane & 31, half = lane >> 5;
        bool valid = row < NSPARSE;
        int srow = valid ? row : 0;
        int idxv[8];
        #pragma unroll
        for (int li = 0; li < 8; ++li)
            idxv[li] = sparse[(sbase + w * 8 + li) * NSPARSE + srow];

        float4 Ca[4], Cb[4], Na[4], Nb[4];
        {
            const float* rp = tables + ((long)srow * VOCAB + idxv[0]) * EMB + half * 8;
            #pragma unroll
            for (int t = 0; t < 4; ++t) {
                Ca[t] = *(const float4*)(rp + t * 16);
                Cb[t] = *(const float4*)(rp + t * 16 + 4);
            }
        }
        #pragma unroll
        for (int li = 0; li < 8; ++li) {
            if (li < 7) {
                const float* rp = tables + ((long)srow * VOCAB + idxv[li + 1]) * EMB + half * 8;
                #pragma unroll
                for (int t = 0; t < 4; ++t) {
                    Na[t] = *(const float4*)(rp + t * 16);
                    Nb[t] = *(const float4*)(rp + t * 16 + 4);
                }
            }
            f32x16 acc = {};
            #pragma unroll
            for (int t = 0; t < 4; ++t) {
                float va[8] = {Ca[t].x, Ca[t].y, Ca[t].z, Ca[t].w,
                               Cb[t].x, Cb[t].y, Cb[t].z, Cb[t].w};
                bf16x8 f;
                #pragma unroll
                for (int j = 0; j < 8; ++j) f[j] = f2bf(valid ? va[j] : 0.f);
                acc = __builtin_amdgcn_mfma_f32_32x32x16_bf16(f, f, acc, 0, 0, 0);
            }
            int c = row;
            if (c < NSPARSE) {
                #pragma unroll
                for (int reg = 0; reg < 16; ++reg) {
                    int r = (reg & 3) + 8 * (reg >> 2) + 4 * half;
                    if (r < c) {
                        int p = r * (2 * NSPARSE - r - 1) / 2 + (c - r - 1);
                        As[(w * 8 + li) * ASTR + 64 + p] = f2bf(acc[reg]);
                    }
                }
            }
            #pragma unroll
            for (int t = 0; t < 4; ++t) { Ca[t] = Na[t]; Cb[t] = Nb[t]; }
        }
    };

    // ---- MLP chain: 32 rows, all in LDS ----
    auto mlp_phase = [&]() {
        // phase 0: X1 = relu(Ds @ W0^T + b0): 32x512, K=32 (B read from global)
        {
            bf16x8 a = *(const bf16x8*)&Ds[(wr * 16 + lr) * 32 + lg * 8];
            f32x4 acc[16] = {};
            #pragma unroll
            for (int ni = 0; ni < 16; ++ni) {
                bf16x8 b = *(const bf16x8*)(W0t + (size_t)(wc * 256 + ni * 16 + lr) * 32 + lg * 8);
                acc[ni] = __builtin_amdgcn_mfma_f32_16x16x32_bf16(a, b, acc[ni], 0, 0, 0);
            }
            #pragma unroll
            for (int ni = 0; ni < 16; ++ni) {
                int col = wc * 256 + ni * 16 + lr;
                float bv = b0[col];
                #pragma unroll
                for (int j = 0; j < 4; ++j) {
                    int r = wr * 16 + lg * 4 + j;
                    X1s[r * X1STR + col] = f2bf(fmaxf(acc[ni][j] + bv, 0.f));
                }
            }
        }
        // phase 1: X2 = relu(X1 @ W1^T + b1): 32x256, K=512 (16 steps)
        {
            f32x4 acc[8] = {};
            for (int k0 = 0; k0 < 512; k0 += 32) {
                #pragma unroll
                for (int rd = 0; rd < 4; ++rd) {
                    int slot = rd * 256 + tid;
                    int n = slot >> 2, kc = slot & 3;
                    gload_lds16(W1t + (size_t)n * 512 + k0 + (kc ^ (n & 3)) * 8, &Bst[slot * 8]);
                }
                __syncthreads();
                bf16x8 a = *(const bf16x8*)&X1s[(wr * 16 + lr) * X1STR + k0 + lg * 8];
                #pragma unroll
                for (int ni = 0; ni < 8; ++ni) {
                    int n = wc * 128 + ni * 16 + lr;
                    bf16x8 b = *(const bf16x8*)&Bst[n * 32 + swz];
                    acc[ni] = __builtin_amdgcn_mfma_f32_16x16x32_bf16(a, b, acc[ni], 0, 0, 0);
                }
                __syncthreads();
            }
            #pragma unroll
            for (int ni = 0; ni < 8; ++ni) {
                int col = wc * 128 + ni * 16 + lr;
                float bv = b1[col];
                #pragma unroll
                for (int j = 0; j < 4; ++j) {
                    int r = wr * 16 + lg * 4 + j;
                    X2s[r * X2STR + col] = f2bf(fmaxf(acc[ni][j] + bv, 0.f));
                }
            }
        }
        // phase 2: dense_out = relu(X2 @ W2^T + b2): 32x64, K=256 (8 steps)
        {
            f32x4 acc[2] = {};
            for (int k0 = 0; k0 < 256; k0 += 32) {
                {
                    int n = tid >> 2, kc = tid & 3;
                    gload_lds16(W2t + (size_t)n * 256 + k0 + (kc ^ (n & 3)) * 8, &Bst[tid * 8]);
                }
                __syncthreads();
                bf16x8 a = *(const bf16x8*)&X2s[(wr * 16 + lr) * X2STR + k0 + lg * 8];
                #pragma unroll
                for (int ni = 0; ni < 2; ++ni) {
                    int n = wc * 32 + ni * 16 + lr;
                    bf16x8 b = *(const bf16x8*)&Bst[n * 32 + swz];
                    acc[ni] = __builtin_amdgcn_mfma_f32_16x16x32_bf16(a, b, acc[ni], 0, 0, 0);
                }
                __syncthreads();
            }
            #pragma unroll
            for (int ni = 0; ni < 2; ++ni) {
                int col = wc * 32 + ni * 16 + lr;
                float bv = b2[col];
                #pragma unroll
                for (int j = 0; j < 4; ++j) {
                    int r = wr * 16 + lg * 4 + j;
                    As[r * ASTR + col] = f2bf(fmaxf(acc[ni][j] + bv, 0.f));
                }
            }
        }
    };

    // parity stagger: half the blocks gather first, half compute first
    if (blockIdx.x & 1) { mlp_phase(); gram_phase(); }
    else                { gram_phase(); mlp_phase(); }

    // ---- top GEMM: out(32x256) = As(32xK416) @ Wtt^T + bt ----
    {
        f32x4 acc[8] = {};
        for (int k0 = 0; k0 < KTOP; k0 += 32) {
            #pragma unroll
            for (int rd = 0; rd < 4; ++rd) {
                int slot = rd * 256 + tid;
                int n = slot >> 2, kc = slot & 3;
                gload_lds16(Wtt + (size_t)n * KTOP + k0 + (kc ^ (n & 3)) * 8, &Bst[slot * 8]);
            }
            __syncthreads();
            bf16x8 a = *(const bf16x8*)&As[(wr * 16 + lr) * ASTR + k0 + lg * 8];
            #pragma unroll
            for (int ni = 0; ni < 8; ++ni) {
                int n = wc * 128 + ni * 16 + lr;
                bf16x8 b = *(const bf16x8*)&Bst[n * 32 + swz];
                acc[ni] = __builtin_amdgcn_mfma_f32_16x16x32_bf16(a, b, acc[ni], 0, 0, 0);
            }
            __syncthreads();
        }
        #pragma unroll
        for (int ni = 0; ni < 8; ++ni) {
            int col = wc * 128 + ni * 16 + lr;
            float bv = bt[col];
            #pragma unroll
            for (int j = 0; j < 4; ++j) {
                int r = wr * 16 + lg * 4 + j;
                out[(size_t)(sbase + r) * 256 + col] = acc[ni][j] + bv;
            }
        }
    }
}

// -------------------------------------------------------------- launch ----
extern "C" void kernel_launch(void* const* d_in, const int* in_sizes, int n_in,
                              void* d_out, int out_size, void* d_ws, size_t ws_size,
                              hipStream_t stream)
{
    const float* dense  = (const float*)d_in[0];
    const int*   sparse = (const int*)  d_in[1];
    const float* tables = (const float*)d_in[2];
    const float* W0     = (const float*)d_in[3];
    const float* b0     = (const float*)d_in[4];
    const float* W1     = (const float*)d_in[5];
    const float* b1     = (const float*)d_in[6];
    const float* W2     = (const float*)d_in[7];
    const float* b2     = (const float*)d_in[8];
    const float* Wt     = (const float*)d_in[9];
    const float* bt     = (const float*)d_in[10];
    float* out = (float*)d_out;

    char* ws = (char*)d_ws;
    short* W0t = (short*)(ws);
    short* W1t = (short*)(ws + 32768);
    short* W2t = (short*)(ws + 294912);
    short* Wtt = (short*)(ws + 327680);

    prep_weights<<<264, 256, 0, stream>>>(W0, W1, W2, Wt, W0t, W1t, W2t, Wtt);

    fused_all<<<BATCH / SPB, 256, 0, stream>>>(sparse, tables, dense,
                                               W0t, b0, W1t, b1, W2t, b2,
                                               Wtt, bt, out);
}